// Round 7
// baseline (45.528 us; speedup 1.0000x reference)
//
#include <hip/hip_runtime.h>
#include <hip/hip_bf16.h>

#define B_   4
#define Hf   128
#define Wf   128
#define HC   32
#define WC   32
#define SR   15
#define PAD  7
#define FRR  139      // fr rows (padded pooled grid height)
#define FRW  144      // fr width: 139 + 5 extra zero cols so corr windows stay in-bounds

typedef float  vfloat4 __attribute__((ext_vector_type(4)));
typedef short  short8  __attribute__((ext_vector_type(8)));

static __device__ __forceinline__ unsigned short f2bf(float x) {
    __hip_bfloat16 h = __float2bfloat16(x);
    unsigned short u; __builtin_memcpy(&u, &h, 2); return u;
}

// ---- fused pooling ----
// blocks [0,1296): f_r_pad = pad(avg_pool(in1,4,1),7) -> (4,139,144,128) bf16 (zeros outside)
// blocks [1296,1808): f_c   = avg_pool(in0,4,4)       -> (4,32,32,128)  bf16
__global__ __launch_bounds__(256) void pool_fused(const float* __restrict__ in0,
                                                  const float* __restrict__ in1,
                                                  unsigned short* __restrict__ fc,
                                                  unsigned short* __restrict__ fr) {
    int bid = blockIdx.x;
    if (bid < 4 * 18 * 18) {
        int yt = bid % 18;
        int xt = (bid / 18) % 18;
        int b  = bid / (18 * 18);
        int c4 = threadIdx.x & 31;
        int x  = xt * 8 + (threadIdx.x >> 5);    // 0..143
        int y0 = yt * 8;
        bool xin = (x >= PAD) && (x < PAD + 125);

        float4 h[11];
        if (xin) {
            int xi = x - PAD;
            const float4* base = reinterpret_cast<const float4*>(in1) + (size_t)(b * Hf * Wf) * 32 + c4;
#pragma unroll
            for (int k = 0; k < 11; ++k) {
                int r = y0 - PAD + k;
                r = r < 0 ? 0 : (r > Hf - 1 ? Hf - 1 : r);
                float4 s = make_float4(0.f, 0.f, 0.f, 0.f);
#pragma unroll
                for (int dx = 0; dx < 4; ++dx) {
                    float4 v = base[(size_t)(r * Wf + xi + dx) * 32];
                    s.x += v.x; s.y += v.y; s.z += v.z; s.w += v.w;
                }
                h[k] = s;
            }
        }
        const float sc = 1.0f / 16.0f;
        ushort4* fr4 = reinterpret_cast<ushort4*>(fr);
#pragma unroll
        for (int yy = 0; yy < 8; ++yy) {
            int y = y0 + yy;
            if (y >= FRR) continue;
            ushort4 o = make_ushort4(0, 0, 0, 0);
            if (xin && y >= PAD && y < PAD + 125) {
                o.x = f2bf((h[yy].x + h[yy+1].x + h[yy+2].x + h[yy+3].x) * sc);
                o.y = f2bf((h[yy].y + h[yy+1].y + h[yy+2].y + h[yy+3].y) * sc);
                o.z = f2bf((h[yy].z + h[yy+1].z + h[yy+2].z + h[yy+3].z) * sc);
                o.w = f2bf((h[yy].w + h[yy+1].w + h[yy+2].w + h[yy+3].w) * sc);
            }
            fr4[((size_t)(b * FRR + y) * FRW + x) * 32 + c4] = o;
        }
    } else {
        int t = (bid - 4 * 18 * 18) * 256 + threadIdx.x;   // 512 blocks
        int c4 = t & 31;
        int j  = (t >> 5) & 31;
        int i  = (t >> 10) & 31;
        int b  = t >> 15;
        const float4* in = reinterpret_cast<const float4*>(in0);
        size_t base = ((size_t)(b * Hf + 4 * i) * Wf + 4 * j) * 32 + c4;
        float4 acc = make_float4(0.f, 0.f, 0.f, 0.f);
#pragma unroll
        for (int dy = 0; dy < 4; ++dy)
#pragma unroll
            for (int dx = 0; dx < 4; ++dx) {
                float4 v = in[base + dy * (Wf * 32) + dx * 32];
                acc.x += v.x; acc.y += v.y; acc.z += v.z; acc.w += v.w;
            }
        const float sc = 1.0f / 16.0f;
        ushort4 o;
        o.x = f2bf(acc.x * sc); o.y = f2bf(acc.y * sc);
        o.z = f2bf(acc.z * sc); o.w = f2bf(acc.w * sc);
        reinterpret_cast<ushort4*>(fc)[t] = o;
    }
}

// ---- correlation via MFMA ----
// block = (b, i, jq): 8 cells j = 8jq..8jq+7. Per u: C[16x48] = A(fc 16x128) x B(fr window).
// 3 waves (192 thr), wave = N-tile. 3-buffer staged fr rows via global_load_lds (swizzled src).
__global__ __launch_bounds__(192) void corr_mfma(const unsigned short* __restrict__ fc,
                                                 const unsigned short* __restrict__ fr,
                                                 float* __restrict__ out) {
    int blk  = blockIdx.x;
    int cell = (blk & 7) * 64 + (blk >> 3);      // XCD swizzle (512 % 8 == 0)
    int jq = cell & 3;
    int i  = (cell >> 2) & 31;
    int b  = cell >> 7;
    int j0 = jq * 8;

    int tid  = threadIdx.x;
    int lane = tid & 63;
    int wv   = tid >> 6;                         // 0..2 = N-tile

    __shared__ __align__(16) unsigned short stage[3][6144];  // 3 x 12288 B (48 w x 128 c bf16)
    __shared__ __align__(16) float rep[8][900];              // 8 cells x (4 dj x 225) replicated

    // A fragments: lane holds A[lane&15][kk*32 + (lane>>4)*8 .. +8]
    const short8* fc8 = reinterpret_cast<const short8*>(fc);
    int arow = (b * HC + i) * WC + j0 + (lane & 15);
    short8 afrag[4];
#pragma unroll
    for (int kk = 0; kk < 4; ++kk)
        afrag[kk] = fc8[(size_t)arow * 16 + kk * 4 + (lane >> 4)];
    asm volatile("s_waitcnt vmcnt(0)" ::: "memory");

    auto STAGE = [&](int u, int bi) {
        const char* gsrc = (const char*)(fr + ((size_t)((b * FRR + 4 * i + u) * FRW) + 4 * j0) * 128);
        char* lbase = (char*)&stage[bi][0];
#pragma unroll
        for (int k = 0; k < 4; ++k) {
            int d   = k * 3072 + tid * 16;                    // linear LDS dest
            int src = d ^ (((d >> 8) & 7) << 4);              // inverse-swizzled source
            __builtin_amdgcn_global_load_lds(
                (const __attribute__((address_space(1))) unsigned int*)(gsrc + src),
                (__attribute__((address_space(3))) unsigned int*)(lbase + d), 16, 0, 0);
        }
    };

    STAGE(0, 0);
    STAGE(1, 1);
    const float lrs = 1.0f / 128.0f;

#pragma unroll
    for (int u = 0; u < 15; ++u) {
        __builtin_amdgcn_s_barrier();            // prev compute done -> safe to overwrite (u+2)%3
        __builtin_amdgcn_sched_barrier(0);
        if (u < 13) {
            STAGE(u + 2, (u + 2) % 3);
            asm volatile("s_waitcnt vmcnt(8)" ::: "memory");   // buf u landed; u+1,u+2 in flight
        } else if (u == 13) {
            asm volatile("s_waitcnt vmcnt(4)" ::: "memory");
        } else {
            asm volatile("s_waitcnt vmcnt(0)" ::: "memory");
        }

        const char* sb = (const char*)&stage[u % 3][0];
        vfloat4 acc = {0.f, 0.f, 0.f, 0.f};
#pragma unroll
        for (int kk = 0; kk < 4; ++kk) {
            int lin  = wv * 4096 + (lane & 15) * 256 + (lane >> 4) * 16 + kk * 64;
            int addr = lin ^ ((lane & 7) << 4);               // matches staged swizzle
            short8 bfrag = *reinterpret_cast<const short8*>(sb + addr);
            acc = __builtin_amdgcn_mfma_f32_16x16x32_bf16(afrag[kk], bfrag, acc, 0, 0, 0);
        }
        // extract: C col = lane&15 (w), row = (lane>>4)*4 + r (j)
#pragma unroll
        for (int r = 0; r < 4; ++r) {
            int jrow = (lane >> 4) * 4 + r;
            int v    = wv * 16 + (lane & 15) - 4 * jrow;
            if (jrow < 8 && v >= 0 && v < SR) {
                float c   = acc[r] * lrs;
                float val = c > 0.f ? c : 0.1f * c;
                float* rp = &rep[jrow][u * SR + v];
                rp[0] = val; rp[225] = val; rp[450] = val; rp[675] = val;
            }
        }
    }
    __syncthreads();

    // copy-out: rep (8 x 900 = 1800 float4, contiguous) -> 4 identical pixel rows
    const vfloat4* rep4 = reinterpret_cast<const vfloat4*>(&rep[0][0]);
    vfloat4* out4 = reinterpret_cast<vfloat4*>(out);
    size_t orow0 = ((size_t)(b * Hf + 4 * i) * Wf + 4 * j0) * 225 / 4;
    for (int q = tid; q < 1800; q += 192) {
        vfloat4 val = rep4[q];
#pragma unroll
        for (int di = 0; di < 4; ++di)
            __builtin_nontemporal_store(val, &out4[orow0 + (size_t)di * (Wf * 225 / 4) + q]);
    }
}

extern "C" void kernel_launch(void* const* d_in, const int* in_sizes, int n_in,
                              void* d_out, int out_size, void* d_ws, size_t ws_size,
                              hipStream_t stream) {
    const float* f0 = (const float*)d_in[0];
    const float* f1 = (const float*)d_in[1];
    float* out = (float*)d_out;

    unsigned short* fc = (unsigned short*)d_ws;                  // 4*32*32*128 bf16 = 1 MB
    unsigned short* fr = fc + (size_t)B_ * HC * WC * 128;        // 4*139*144*128 bf16 = 20.5 MB

    pool_fused<<<4 * 18 * 18 + 512, 256, 0, stream>>>(f0, f1, fc, fr);
    corr_mfma<<<B_ * 32 * 4, 192, 0, stream>>>(fc, fr, out);
}